// Round 1
// baseline (185.633 us; speedup 1.0000x reference)
//
#include <hip/hip_runtime.h>

// Causal attention fwd, B=2 H=16 S=2048 DK=DV=64, fp32 in/out.
// Plan: prep kernel transposes V -> Vt bf16 in d_ws; main kernel is a
// flash-style causal attention with swapped QK^T (mfma(K,Q)) so softmax is
// lane-local, Q/K in bf16 hi+lo split (near-fp32 scores), P/V single bf16.

#define S_LEN   2048
#define D_DIM   64
#define BH_N    32
#define Q_TILE  128
#define KV_TILE 64
#define NEG_BIG (-3.0e38f)
#define CSCALE  0.18033688011112042f   // log2(e)/sqrt(64)

typedef float  f32x16  __attribute__((ext_vector_type(16)));
typedef short  short8v __attribute__((ext_vector_type(8)));
typedef unsigned int   u32;
typedef unsigned short u16;

__device__ __forceinline__ u16 rne_bf16(float f) {
  u32 u = __float_as_uint(f);
  u += 0x7FFFu + ((u >> 16) & 1u);
  return (u16)(u >> 16);
}
__device__ __forceinline__ float bf16f(u16 h) {
  return __uint_as_float(((u32)h) << 16);
}

// ---------------- prep: V[bh][kv][dv] f32 -> Vt[bh][dv][kv] bf16 ----------------
__global__ __launch_bounds__(256) void vtrans_kernel(const float* __restrict__ V,
                                                     u16* __restrict__ Vt) {
  __shared__ __align__(16) float buf[64][68];   // pad 68: 272B row stride, 16B-aligned
  const int bid = blockIdx.x;          // 1024 blocks = 32 bh * 32 kv-tiles
  const int bh  = bid & (BH_N - 1);
  const int kt  = bid >> 5;
  const int kv0 = kt * 64;
  const int t   = threadIdx.x;
  {
    const int r = t >> 2, c0 = (t & 3) * 16;
    const float* src = V + ((size_t)bh * S_LEN + kv0 + r) * D_DIM + c0;
    float4 a0 = *(const float4*)(src + 0);
    float4 a1 = *(const float4*)(src + 4);
    float4 a2 = *(const float4*)(src + 8);
    float4 a3 = *(const float4*)(src + 12);
    *(float4*)&buf[r][c0 + 0]  = a0;
    *(float4*)&buf[r][c0 + 4]  = a1;
    *(float4*)&buf[r][c0 + 8]  = a2;
    *(float4*)&buf[r][c0 + 12] = a3;
  }
  __syncthreads();
  {
    const int dv = t >> 2, kc = (t & 3) * 16;
    u32 w[8];
    #pragma unroll
    for (int j = 0; j < 8; ++j) {
      u16 h0 = rne_bf16(buf[kc + 2 * j][dv]);
      u16 h1 = rne_bf16(buf[kc + 2 * j + 1][dv]);
      w[j] = (u32)h0 | ((u32)h1 << 16);
    }
    u16* dst = Vt + ((size_t)bh * D_DIM + dv) * S_LEN + kv0 + kc;
    *(uint4*)(dst + 0) = make_uint4(w[0], w[1], w[2], w[3]);
    *(uint4*)(dst + 8) = make_uint4(w[4], w[5], w[6], w[7]);
  }
}

// row-major [64][64] bf16 LDS tile, XOR-swizzled: byte ^= (row&7)<<4
__device__ __forceinline__ short8v lds_frag(const u16* base, int row, int colByte) {
  u32 off = (u32)(row * 128 + colByte);
  off ^= ((u32)(row & 7)) << 4;
  return *(const short8v*)((const char*)base + off);
}

// ---------------- main flash attention ----------------
__global__ __launch_bounds__(256, 2) void attn_kernel(const float* __restrict__ Q,
                                                      const float* __restrict__ K,
                                                      const u16* __restrict__ Vt,
                                                      float* __restrict__ Out) {
  __shared__ __align__(16) u16 KhS[64 * 64];
  __shared__ __align__(16) u16 KlS[64 * 64];
  __shared__ __align__(16) u16 VtS[64 * 64];

  const int bid = blockIdx.x;          // 512 = 32 bh * 16 qt
  const int bh  = bid & 31;
  const int qt  = 15 - (bid >> 5);     // biggest causal tiles dispatched first
  const int t   = threadIdx.x;
  const int w   = t >> 6;
  const int l   = t & 63;
  const int lo31 = l & 31;
  const int hi  = l >> 5;
  const int qb  = qt * Q_TILE + w * 32;
  const int q   = qb + lo31;

  // Q fragments (scaled by log2e/8, split hi/lo bf16). B-frag: col=q=l&31, k=d=(l>>5)*8+j
  short8v qh[4], ql[4];
  {
    const float* qp = Q + ((size_t)bh * S_LEN + q) * D_DIM;
    #pragma unroll
    for (int kk = 0; kk < 4; ++kk) {
      const int d0 = kk * 16 + hi * 8;
      float4 a = *(const float4*)(qp + d0);
      float4 b = *(const float4*)(qp + d0 + 4);
      float fv[8] = {a.x, a.y, a.z, a.w, b.x, b.y, b.z, b.w};
      #pragma unroll
      for (int j = 0; j < 8; ++j) {
        float v = fv[j] * CSCALE;
        u16 h = rne_bf16(v);
        qh[kk][j] = (short)h;
        ql[kk][j] = (short)rne_bf16(v - bf16f(h));
      }
    }
  }

  f32x16 o0 = {};      // O^T rows dv 0..31  (col=q=l&31, row=(i&3)+8*(i>>2)+4*hi)
  f32x16 o1 = {};      // O^T rows dv 32..63
  float m_run = NEG_BIG;
  float r_sum = 0.0f;

  const int NT = 2 * (qt + 1);
  for (int T = 0; T < NT; ++T) {
    const int kb = T * KV_TILE;
    __syncthreads();
    { // stage K (f32 -> bf16 hi/lo) and Vt (bf16 copy) into swizzled LDS
      const int sr = t >> 2, sc = (t & 3) * 16;
      const float* kg = K + ((size_t)bh * S_LEN + kb + sr) * D_DIM + sc;
      float4 a0 = *(const float4*)(kg + 0);
      float4 a1 = *(const float4*)(kg + 4);
      float4 a2 = *(const float4*)(kg + 8);
      float4 a3 = *(const float4*)(kg + 12);
      float fv[16] = {a0.x, a0.y, a0.z, a0.w, a1.x, a1.y, a1.z, a1.w,
                      a2.x, a2.y, a2.z, a2.w, a3.x, a3.y, a3.z, a3.w};
      u32 hw[8], lw[8];
      #pragma unroll
      for (int j = 0; j < 8; ++j) {
        float x0 = fv[2 * j], x1 = fv[2 * j + 1];
        u16 h0 = rne_bf16(x0), h1 = rne_bf16(x1);
        u16 l0 = rne_bf16(x0 - bf16f(h0));
        u16 l1 = rne_bf16(x1 - bf16f(h1));
        hw[j] = (u32)h0 | ((u32)h1 << 16);
        lw[j] = (u32)l0 | ((u32)l1 << 16);
      }
      const u32 base = (u32)(sr * 128 + sc * 2);
      const u32 sw   = ((u32)(sr & 7)) << 4;
      *(uint4*)((char*)KhS + ((base +  0) ^ sw)) = make_uint4(hw[0], hw[1], hw[2], hw[3]);
      *(uint4*)((char*)KhS + ((base + 16) ^ sw)) = make_uint4(hw[4], hw[5], hw[6], hw[7]);
      *(uint4*)((char*)KlS + ((base +  0) ^ sw)) = make_uint4(lw[0], lw[1], lw[2], lw[3]);
      *(uint4*)((char*)KlS + ((base + 16) ^ sw)) = make_uint4(lw[4], lw[5], lw[6], lw[7]);
      const u16* vg = Vt + ((size_t)bh * D_DIM + sr) * S_LEN + kb + sc;
      uint4 v0 = *(const uint4*)(vg + 0);
      uint4 v1 = *(const uint4*)(vg + 8);
      *(uint4*)((char*)VtS + ((base +  0) ^ sw)) = v0;
      *(uint4*)((char*)VtS + ((base + 16) ^ sw)) = v1;
    }
    __syncthreads();

    #pragma unroll
    for (int sub = 0; sub < 2; ++sub) {
      const int kbs = kb + sub * 32;
      if (kbs <= qb) {                       // causal: skip fully-masked subtiles
        const bool diag = (kbs == qb);
        // S^T[kv][q] = sum_d K[kv][d] * (Q*C)[q][d], hi/lo split (3 mfma / k-step)
        f32x16 sA = {};
        f32x16 sB = {};
        const int krow = sub * 32 + lo31;
        #pragma unroll
        for (int kk = 0; kk < 4; ++kk) {
          const int cb = kk * 32 + hi * 16;
          short8v kh = lds_frag(KhS, krow, cb);
          short8v kl = lds_frag(KlS, krow, cb);
          sA = __builtin_amdgcn_mfma_f32_32x32x16_bf16(kh, qh[kk], sA, 0, 0, 0);
          sB = __builtin_amdgcn_mfma_f32_32x32x16_bf16(kh, ql[kk], sB, 0, 0, 0);
          sA = __builtin_amdgcn_mfma_f32_32x32x16_bf16(kl, qh[kk], sA, 0, 0, 0);
        }
        float sv[16];
        #pragma unroll
        for (int i = 0; i < 16; ++i) sv[i] = sA[i] + sB[i];
        if (diag) {
          #pragma unroll
          for (int i = 0; i < 16; ++i) {
            const int kvloc = (i & 3) + 8 * (i >> 2) + 4 * hi;  // C/D row map (m101)
            if (kvloc > lo31) sv[i] = NEG_BIG;
          }
        }
        // online softmax: lane pair (l, l+32) holds one q-row's 32 kv scores
        float mt = sv[0];
        #pragma unroll
        for (int i = 1; i < 16; ++i) mt = fmaxf(mt, sv[i]);
        mt = fmaxf(mt, __shfl_xor(mt, 32, 64));
        const float m_new   = fmaxf(m_run, mt);
        const float rescale = __builtin_amdgcn_exp2f(m_run - m_new);
        m_run = m_new;
        r_sum *= rescale;
        #pragma unroll
        for (int i = 0; i < 16; ++i) { o0[i] = o0[i] * rescale; o1[i] = o1[i] * rescale; }
        u16 pb[16];
        float psum = 0.0f;
        #pragma unroll
        for (int i = 0; i < 16; ++i) {
          float p = __builtin_amdgcn_exp2f(sv[i] - m_new);
          u16 h = rne_bf16(p);
          pb[i] = h;
          psum += bf16f(h);    // denominator from rounded P for consistency
        }
        psum += __shfl_xor(psum, 32, 64);
        r_sum += psum;
        // repack P (C/D layout) -> B-frag layout via lane l <-> l+32 exchange
        u32 c[8];
        #pragma unroll
        for (int i = 0; i < 8; ++i) c[i] = (u32)pb[2 * i] | ((u32)pb[2 * i + 1] << 16);
        u32 x[8];
        #pragma unroll
        for (int i = 0; i < 8; ++i) x[i] = (u32)__shfl_xor((int)c[i], 32, 64);
        const bool lolane = (hi == 0);
        u32 pw[8];
        pw[0] = lolane ? c[0] : x[2];
        pw[1] = lolane ? c[1] : x[3];
        pw[2] = lolane ? x[0] : c[2];
        pw[3] = lolane ? x[1] : c[3];
        pw[4] = lolane ? c[4] : x[6];
        pw[5] = lolane ? c[5] : x[7];
        pw[6] = lolane ? x[4] : c[6];
        pw[7] = lolane ? x[5] : c[7];
        union { u32 u[4]; short8v v; } cv0, cv1;
        cv0.u[0] = pw[0]; cv0.u[1] = pw[1]; cv0.u[2] = pw[2]; cv0.u[3] = pw[3];
        cv1.u[0] = pw[4]; cv1.u[1] = pw[5]; cv1.u[2] = pw[6]; cv1.u[3] = pw[7];
        // O^T += V^T * P   (A = Vt rows, B = P frag)
        #pragma unroll
        for (int ks = 0; ks < 2; ++ks) {
          const int cbv = sub * 64 + ks * 32 + hi * 16;
          short8v va = lds_frag(VtS, lo31,      cbv);
          short8v vb = lds_frag(VtS, 32 + lo31, cbv);
          short8v pf = (ks == 0) ? cv0.v : cv1.v;
          o0 = __builtin_amdgcn_mfma_f32_32x32x16_bf16(va, pf, o0, 0, 0, 0);
          o1 = __builtin_amdgcn_mfma_f32_32x32x16_bf16(vb, pf, o1, 0, 0, 0);
        }
      }
    }
  }

  const float inv = 1.0f / r_sum;
  float* op = Out + ((size_t)bh * S_LEN + q) * D_DIM;
  #pragma unroll
  for (int g = 0; g < 4; ++g) {
    float4 s0 = make_float4(o0[4 * g + 0] * inv, o0[4 * g + 1] * inv,
                            o0[4 * g + 2] * inv, o0[4 * g + 3] * inv);
    float4 s1 = make_float4(o1[4 * g + 0] * inv, o1[4 * g + 1] * inv,
                            o1[4 * g + 2] * inv, o1[4 * g + 3] * inv);
    *(float4*)(op + g * 8 + hi * 4)      = s0;   // dv = 8g + 4*hi + 0..3
    *(float4*)(op + 32 + g * 8 + hi * 4) = s1;   // dv + 32
  }
}

extern "C" void kernel_launch(void* const* d_in, const int* in_sizes, int n_in,
                              void* d_out, int out_size, void* d_ws, size_t ws_size,
                              hipStream_t stream) {
  const float* Q = (const float*)d_in[0];
  const float* K = (const float*)d_in[1];
  const float* V = (const float*)d_in[2];
  // d_in[3] = tril mask: handled analytically (causal), not read.
  float* Out = (float*)d_out;
  u16* Vt = (u16*)d_ws;                       // needs 32*64*2048*2 B = 8.39 MB
  vtrans_kernel<<<dim3(BH_N * (S_LEN / 64)), dim3(256), 0, stream>>>(V, Vt);
  attn_kernel<<<dim3(BH_N * (S_LEN / Q_TILE)), dim3(256), 0, stream>>>(Q, K, Vt, Out);
}

// Round 3
// 158.871 us; speedup vs baseline: 1.1685x; 1.1685x over previous
//
#include <hip/hip_runtime.h>

// Causal attention fwd, B=2 H=16 S=2048 DK=DV=64, fp32 in/out.
// R3 = R2 with compile fixes: cvt_pkrtz returns __fp16x2 (not _Float16x2);
// permlane32_swap return captured with auto.
// f16 pipeline (1 MFMA per k-step), double-buffered LDS with async-STAGE
// split, 64-wide online softmax + defer-max (THR=8), permlane32_swap repack,
// setprio around MFMA clusters.

#define S_LEN   2048
#define D_DIM   64
#define BH_N    32
#define Q_TILE  128
#define KV_TILE 64
#define NEG_BIG (-3.0e38f)
#define CSCALE  0.18033688011112042f   // log2(e)/sqrt(64)

typedef float     f32x16 __attribute__((ext_vector_type(16)));
typedef _Float16  f16x8  __attribute__((ext_vector_type(8)));
typedef __fp16    fp16x2 __attribute__((ext_vector_type(2)));
typedef unsigned int   u32;
typedef unsigned short u16;

__device__ __forceinline__ u32 pkrtz2(float a, float b) {
  union { fp16x2 h; u32 u; } U;
  U.h = __builtin_amdgcn_cvt_pkrtz(a, b);
  return U.u;
}

// swap a[32:63] <-> b[0:31] (v_permlane32_swap_b32)
__device__ __forceinline__ void plswap(u32& a, u32& b) {
  auto r = __builtin_amdgcn_permlane32_swap((int)a, (int)b, false, false);
  a = (u32)r[0]; b = (u32)r[1];
}

__device__ __forceinline__ f32x16 mfma16(f16x8 a, f16x8 b, f32x16 c) {
  return __builtin_amdgcn_mfma_f32_32x32x16_f16(a, b, c, 0, 0, 0);
}

// row-major [64 rows][128B] LDS tile, XOR-swizzled: byte ^= (row&7)<<4
__device__ __forceinline__ f16x8 lds_frag(const u16* base, int row, int colByte) {
  u32 off = (u32)(row * 128 + colByte);
  off ^= ((u32)(row & 7)) << 4;
  return *(const f16x8*)((const char*)base + off);
}

// ---------------- prep: V[bh][kv][dv] f32 -> Vt[bh][dv][kv] f16 ----------------
__global__ __launch_bounds__(256) void vtrans_kernel(const float* __restrict__ V,
                                                     u16* __restrict__ Vt) {
  __shared__ __align__(16) float buf[64][68];
  const int bid = blockIdx.x;          // 1024 = 32 bh * 32 kv-tiles
  const int bh  = bid & (BH_N - 1);
  const int kv0 = (bid >> 5) * 64;
  const int t   = threadIdx.x;
  {
    const int r = t >> 2, c0 = (t & 3) * 16;
    const float* src = V + ((size_t)bh * S_LEN + kv0 + r) * D_DIM + c0;
    float4 a0 = *(const float4*)(src + 0);
    float4 a1 = *(const float4*)(src + 4);
    float4 a2 = *(const float4*)(src + 8);
    float4 a3 = *(const float4*)(src + 12);
    *(float4*)&buf[r][c0 + 0]  = a0;
    *(float4*)&buf[r][c0 + 4]  = a1;
    *(float4*)&buf[r][c0 + 8]  = a2;
    *(float4*)&buf[r][c0 + 12] = a3;
  }
  __syncthreads();
  {
    const int dv = t >> 2, kc = (t & 3) * 16;
    u32 w[8];
    #pragma unroll
    for (int j = 0; j < 8; ++j)
      w[j] = pkrtz2(buf[kc + 2 * j][dv], buf[kc + 2 * j + 1][dv]);
    u16* dst = Vt + ((size_t)bh * D_DIM + dv) * S_LEN + kv0 + kc;
    *(uint4*)(dst + 0) = make_uint4(w[0], w[1], w[2], w[3]);
    *(uint4*)(dst + 8) = make_uint4(w[4], w[5], w[6], w[7]);
  }
}

// ---------------- main flash attention ----------------
__global__ __launch_bounds__(256, 2) void attn_kernel(const float* __restrict__ Q,
                                                      const float* __restrict__ K,
                                                      const u16* __restrict__ Vt,
                                                      float* __restrict__ Out) {
  __shared__ __align__(16) u16 KS[2][64 * 64];   // f16 K tiles, dbuf
  __shared__ __align__(16) u16 VS[2][64 * 64];   // f16 V^T tiles, dbuf

  const int bid = blockIdx.x;          // 512 = 32 bh * 16 qt
  const int bh  = bid & 31;
  const int qt  = 15 - (bid >> 5);     // biggest causal tiles first
  const int t   = threadIdx.x;
  const int w   = t >> 6;
  const int lo31 = t & 31;
  const int hi  = (t >> 5) & 1;
  const int qb  = qt * Q_TILE + w * 32;
  const int q   = qb + lo31;

  // Q fragments (f16, scale folded). B-frag: col=q=lane&31, k=d = kk*16 + hi*8 + j
  f16x8 qf[4];
  {
    const float* qp = Q + ((size_t)bh * S_LEN + q) * D_DIM;
    #pragma unroll
    for (int kk = 0; kk < 4; ++kk) {
      const int dd = kk * 16 + hi * 8;
      float4 a = *(const float4*)(qp + dd);
      float4 b = *(const float4*)(qp + dd + 4);
      union { u32 u[4]; f16x8 v; } U;
      U.u[0] = pkrtz2(a.x * CSCALE, a.y * CSCALE);
      U.u[1] = pkrtz2(a.z * CSCALE, a.w * CSCALE);
      U.u[2] = pkrtz2(b.x * CSCALE, b.y * CSCALE);
      U.u[3] = pkrtz2(b.z * CSCALE, b.w * CSCALE);
      qf[kk] = U.v;
    }
  }

  f32x16 o0 = {};      // O^T rows dv 0..31 (col=q, row=(i&3)+8*(i>>2)+4*hi)
  f32x16 o1 = {};      // O^T rows dv 32..63
  float m_run = NEG_BIG;
  float r_sum = 0.0f;

  // staging regs (issue-early / commit-late, T14)
  const int sr  = t >> 2;
  const int sc4 = (t & 3) * 16;        // element offset of this thread's chunk
  float4 ka0, ka1, ka2, ka3;
  uint4  va0, va1;

  auto issue = [&](int kb) {
    const float* kg = K + ((size_t)bh * S_LEN + kb + sr) * D_DIM + sc4;
    ka0 = *(const float4*)(kg + 0);
    ka1 = *(const float4*)(kg + 4);
    ka2 = *(const float4*)(kg + 8);
    ka3 = *(const float4*)(kg + 12);
    const u16* vg = Vt + ((size_t)bh * D_DIM + sr) * S_LEN + kb + sc4;
    va0 = *(const uint4*)(vg + 0);
    va1 = *(const uint4*)(vg + 8);
  };
  auto commit = [&](int b) {
    const u32 base = (u32)(sr * 128 + sc4 * 2);
    const u32 sw   = ((u32)(sr & 7)) << 4;
    const u32 a0 = base ^ sw, a1 = (base + 16) ^ sw;
    uint4 k0 = make_uint4(pkrtz2(ka0.x, ka0.y), pkrtz2(ka0.z, ka0.w),
                          pkrtz2(ka1.x, ka1.y), pkrtz2(ka1.z, ka1.w));
    uint4 k1 = make_uint4(pkrtz2(ka2.x, ka2.y), pkrtz2(ka2.z, ka2.w),
                          pkrtz2(ka3.x, ka3.y), pkrtz2(ka3.z, ka3.w));
    *(uint4*)((char*)KS[b] + a0) = k0;
    *(uint4*)((char*)KS[b] + a1) = k1;
    *(uint4*)((char*)VS[b] + a0) = va0;
    *(uint4*)((char*)VS[b] + a1) = va1;
  };

  issue(0);
  commit(0);
  __syncthreads();

  const int NT = 2 * (qt + 1);
  for (int T = 0; T < NT; ++T) {
    const int cur = T & 1;
    const int kb  = T * KV_TILE;
    if (T + 1 < NT) issue((T + 1) * KV_TILE);   // hide HBM under compute

    if (kb <= qb) {
      const bool have1 = (kb + 32 <= qb);
      const bool dg0   = (kb == qb);
      const bool dg1   = (kb + 32 == qb);
      const u16* Kc = KS[cur];
      const u16* Vc = VS[cur];

      f32x16 s0 = {}, s1 = {};
      __builtin_amdgcn_s_setprio(1);
      #pragma unroll
      for (int kk = 0; kk < 4; ++kk) {
        f16x8 kf = lds_frag(Kc, lo31, kk * 32 + hi * 16);
        s0 = mfma16(kf, qf[kk], s0);
      }
      if (have1) {
        #pragma unroll
        for (int kk = 0; kk < 4; ++kk) {
          f16x8 kf = lds_frag(Kc, 32 + lo31, kk * 32 + hi * 16);
          s1 = mfma16(kf, qf[kk], s1);
        }
      }
      __builtin_amdgcn_s_setprio(0);

      if (dg0) {
        #pragma unroll
        for (int i = 0; i < 16; ++i) {
          const int kvloc = (i & 3) + 8 * (i >> 2) + 4 * hi;
          if (kvloc > lo31) s0[i] = NEG_BIG;
        }
      }
      if (have1 && dg1) {
        #pragma unroll
        for (int i = 0; i < 16; ++i) {
          const int kvloc = (i & 3) + 8 * (i >> 2) + 4 * hi;
          if (kvloc > lo31) s1[i] = NEG_BIG;
        }
      }

      // --- 64-wide online softmax (lane pair l, l+32 = one q-row) ---
      float t8[8];
      #pragma unroll
      for (int i = 0; i < 8; ++i) t8[i] = fmaxf(s0[i], s0[i + 8]);
      if (have1) {
        #pragma unroll
        for (int i = 0; i < 8; ++i) t8[i] = fmaxf(t8[i], fmaxf(s1[i], s1[i + 8]));
      }
      float t4a = fmaxf(t8[0], t8[4]), t4b = fmaxf(t8[1], t8[5]);
      float t4c = fmaxf(t8[2], t8[6]), t4d = fmaxf(t8[3], t8[7]);
      float mt = fmaxf(fmaxf(t4a, t4b), fmaxf(t4c, t4d));
      mt = fmaxf(mt, __shfl_xor(mt, 32, 64));

      if (!__all(mt <= m_run + 8.0f)) {        // defer-max (T13, THR=8)
        const float mn = fmaxf(m_run, mt);
        const float rs = __builtin_amdgcn_exp2f(m_run - mn);
        m_run = mn;
        r_sum *= rs;
        #pragma unroll
        for (int i = 0; i < 16; ++i) { o0[i] *= rs; o1[i] *= rs; }
      }

      float psum = 0.0f;
      u32 c0w[8], c1w[8];
      #pragma unroll
      for (int j = 0; j < 8; ++j) {
        float pa = __builtin_amdgcn_exp2f(s0[2 * j]     - m_run);
        float pb = __builtin_amdgcn_exp2f(s0[2 * j + 1] - m_run);
        psum += pa + pb;
        c0w[j] = pkrtz2(pa, pb);
      }
      if (have1) {
        #pragma unroll
        for (int j = 0; j < 8; ++j) {
          float pa = __builtin_amdgcn_exp2f(s1[2 * j]     - m_run);
          float pb = __builtin_amdgcn_exp2f(s1[2 * j + 1] - m_run);
          psum += pa + pb;
          c1w[j] = pkrtz2(pa, pb);
        }
      }
      psum += __shfl_xor(psum, 32, 64);
      r_sum += psum;

      // repack P (C/D layout) -> PV B-frags via permlane32_swap (T12)
      plswap(c0w[0], c0w[2]); plswap(c0w[1], c0w[3]);
      plswap(c0w[4], c0w[6]); plswap(c0w[5], c0w[7]);
      union { u32 u[4]; f16x8 v; } B0, B1;
      B0.u[0] = c0w[0]; B0.u[1] = c0w[1]; B0.u[2] = c0w[2]; B0.u[3] = c0w[3];
      B1.u[0] = c0w[4]; B1.u[1] = c0w[5]; B1.u[2] = c0w[6]; B1.u[3] = c0w[7];

      __builtin_amdgcn_s_setprio(1);
      #pragma unroll
      for (int ks = 0; ks < 2; ++ks) {
        f16x8 va = lds_frag(Vc, lo31,      ks * 32 + hi * 16);
        f16x8 vb = lds_frag(Vc, 32 + lo31, ks * 32 + hi * 16);
        f16x8 pf = (ks == 0) ? B0.v : B1.v;
        o0 = mfma16(va, pf, o0);
        o1 = mfma16(vb, pf, o1);
      }
      __builtin_amdgcn_s_setprio(0);

      if (have1) {
        plswap(c1w[0], c1w[2]); plswap(c1w[1], c1w[3]);
        plswap(c1w[4], c1w[6]); plswap(c1w[5], c1w[7]);
        union { u32 u[4]; f16x8 v; } B2, B3;
        B2.u[0] = c1w[0]; B2.u[1] = c1w[1]; B2.u[2] = c1w[2]; B2.u[3] = c1w[3];
        B3.u[0] = c1w[4]; B3.u[1] = c1w[5]; B3.u[2] = c1w[6]; B3.u[3] = c1w[7];
        __builtin_amdgcn_s_setprio(1);
        #pragma unroll
        for (int ks = 0; ks < 2; ++ks) {
          f16x8 va = lds_frag(Vc, lo31,      64 + ks * 32 + hi * 16);
          f16x8 vb = lds_frag(Vc, 32 + lo31, 64 + ks * 32 + hi * 16);
          f16x8 pf = (ks == 0) ? B2.v : B3.v;
          o0 = mfma16(va, pf, o0);
          o1 = mfma16(vb, pf, o1);
        }
        __builtin_amdgcn_s_setprio(0);
      }
    }

    if (T + 1 < NT) commit(cur ^ 1);   // cvt + ds_write after compute (T14)
    __syncthreads();
  }

  const float inv = 1.0f / r_sum;
  float* op = Out + ((size_t)bh * S_LEN + q) * D_DIM;
  #pragma unroll
  for (int g = 0; g < 4; ++g) {
    float4 s0v = make_float4(o0[4 * g + 0] * inv, o0[4 * g + 1] * inv,
                             o0[4 * g + 2] * inv, o0[4 * g + 3] * inv);
    float4 s1v = make_float4(o1[4 * g + 0] * inv, o1[4 * g + 1] * inv,
                             o1[4 * g + 2] * inv, o1[4 * g + 3] * inv);
    *(float4*)(op + g * 8 + hi * 4)      = s0v;   // dv = 8g + 4*hi + 0..3
    *(float4*)(op + 32 + g * 8 + hi * 4) = s1v;   // dv + 32
  }
}

extern "C" void kernel_launch(void* const* d_in, const int* in_sizes, int n_in,
                              void* d_out, int out_size, void* d_ws, size_t ws_size,
                              hipStream_t stream) {
  const float* Q = (const float*)d_in[0];
  const float* K = (const float*)d_in[1];
  const float* V = (const float*)d_in[2];
  // d_in[3] = tril mask: handled analytically (causal), not read.
  float* Out = (float*)d_out;
  u16* Vt = (u16*)d_ws;                       // 32*64*2048*2 B = 8.39 MB
  vtrans_kernel<<<dim3(BH_N * (S_LEN / 64)), dim3(256), 0, stream>>>(V, Vt);
  attn_kernel<<<dim3(BH_N * (S_LEN / Q_TILE)), dim3(256), 0, stream>>>(Q, K, Vt, Out);
}